// Round 3
// baseline (314.629 us; speedup 1.0000x reference)
//
#include <hip/hip_runtime.h>
#include <math.h>

// ---------------------------------------------------------------------------
// GAT, 3 layers, N=50000, E=800000, H=2 heads, D=64/64/32.
// Bucket-CSR build (2-pass, locality-aware; no random 4B scatters);
// barrier-free bf16 MFMA GEMM (frags direct from global; W is L1/L2-resident)
// with fused el/er + bf16-h epilogue; degree-binned aggregation
// (16/32/64 lanes per node), UB=8 gather batching.
// ---------------------------------------------------------------------------

typedef unsigned int uint;
typedef unsigned short ushort;
typedef __attribute__((ext_vector_type(8))) short bf16x8;
typedef __attribute__((ext_vector_type(4))) float f32x4;

#define NBK 196     // buckets = ceil(50000/256); bucket = dst >> 8
#define BCAP 4608   // per-bucket capacity (mean 4082, sigma 64 -> +8 sigma)

__device__ inline uint f2bf(float f) {  // fp32 -> bf16 bits, RNE
    uint u = __float_as_uint(f);
    return (u + 0x7fffu + ((u >> 16) & 1u)) >> 16;
}

__device__ inline uint4 pack8(float4 a, float4 b) {
    return make_uint4(f2bf(a.x) | (f2bf(a.y) << 16), f2bf(a.z) | (f2bf(a.w) << 16),
                      f2bf(b.x) | (f2bf(b.y) << 16), f2bf(b.z) | (f2bf(b.w) << 16));
}

// ---------------------------------------------------------------------------
// Fused pass: blocks [0, nba) = bucketA (edges -> per-bucket append regions);
// blocks [nba, nba+256) = weight transpose+bf16 (independent inputs).
// ---------------------------------------------------------------------------
__global__ __launch_bounds__(256) void buildA_k(
    const int* __restrict__ src, const int* __restrict__ dst, int E,
    int* __restrict__ bcur, uint* __restrict__ bdata, int nba,
    const float* __restrict__ W0, const float* __restrict__ W1,
    const float* __restrict__ W2, const float* __restrict__ Wr,
    ushort* __restrict__ Wt0, ushort* __restrict__ Wt1,
    ushort* __restrict__ Wt2cat) {
    __shared__ int lhist[NBK];
    __shared__ int gbase[NBK];
    const int t = threadIdx.x;
    if ((int)blockIdx.x >= nba) {      // ---- weight-prep blocks ----
        int wb = blockIdx.x - nba;
        if (wb < 128) {                // W0: 32768 elems
            int i = wb * 256 + t;
            int n = i >> 8, k = i & 255;
            Wt0[n * 256 + k] = (ushort)f2bf(W0[k * 128 + n]);
        } else if (wb < 192) {         // W1: 16384
            int i = (wb - 128) * 256 + t;
            int n = i >> 7, k = i & 127;
            Wt1[n * 128 + k] = (ushort)f2bf(W1[k * 128 + n]);
        } else if (wb < 224) {         // W2: 8192
            int i = (wb - 192) * 256 + t;
            int n = i >> 7, k = i & 127;
            Wt2cat[n * 128 + k] = (ushort)f2bf(W2[k * 64 + n]);
        } else {                       // Wres2: 8192
            int i = (wb - 224) * 256 + t;
            int n = i >> 7, k = i & 127;
            Wt2cat[(64 + n) * 128 + k] = (ushort)f2bf(Wr[k * 64 + n]);
        }
        return;
    }
    // ---- bucketA blocks ----
    for (int i = t; i < NBK; i += 256) lhist[i] = 0;
    __syncthreads();
    const int e0 = blockIdx.x * 2048 + t * 8;
    uint payload[8], meta[8];
#pragma unroll
    for (int i = 0; i < 8; ++i) {
        int e = e0 + i;
        if (e < E) {
            int s = src[e], d = dst[e];
            int b = d >> 8;
            int r = atomicAdd(&lhist[b], 1);
            payload[i] = ((uint)s << 8) | (uint)(d & 255);
            meta[i] = ((uint)b << 16) | (uint)r;
        } else {
            meta[i] = 0xffffffffu;
        }
    }
    __syncthreads();
    for (int i = t; i < NBK; i += 256) {
        int c = lhist[i];
        gbase[i] = c ? atomicAdd(&bcur[i], c) : 0;
    }
    __syncthreads();
#pragma unroll
    for (int i = 0; i < 8; ++i) {
        if (meta[i] != 0xffffffffu) {
            int b = meta[i] >> 16;
            int pos = gbase[b] + (int)(meta[i] & 0xffffu);
            if (pos < BCAP) bdata[(size_t)b * BCAP + pos] = payload[i];
        }
    }
}

// ---------------------------------------------------------------------------
// Bucket pass B + inline 196-bucket prefix scan + degree binning.
// One block per bucket -> deg/offs/ssrc (CSR) + class lists nl0/nl1/nl2.
// ---------------------------------------------------------------------------
__global__ __launch_bounds__(256) void bucketB_k(
    const uint* __restrict__ bdata, const int* __restrict__ bcur,
    int* __restrict__ deg, int* __restrict__ offs, int* __restrict__ ssrc,
    int n, int* __restrict__ meta, int* __restrict__ nl0,
    int* __restrict__ nl1, int* __restrict__ nl2) {
    __shared__ int lhist[256], lofs[256], lcur[256], stmp[256];
    __shared__ int lc[3], lb[3], sgb;
    const int b = blockIdx.x, t = threadIdx.x;
    const int cnt = min(bcur[b], BCAP);
    // inline exclusive prefix over the 196 bucket counts -> this bucket's base
    int cv = (t < NBK) ? min(bcur[t], BCAP) : 0;
    stmp[t] = cv;
    lhist[t] = 0;
    if (t < 3) lc[t] = 0;
    __syncthreads();
    for (int o = 1; o < 256; o <<= 1) {
        int add = (t >= o) ? stmp[t - o] : 0;
        __syncthreads();
        stmp[t] += add;
        __syncthreads();
    }
    if (t == 0) sgb = b ? stmp[b - 1] : 0;
    __syncthreads();
    const int gb = sgb;
    const uint* bd = bdata + (size_t)b * BCAP;
    for (int i = t; i < cnt; i += 256)
        atomicAdd(&lhist[bd[i] & 255], 1);
    __syncthreads();
    int v = lhist[t];
    stmp[t] = v;
    __syncthreads();
    for (int o = 1; o < 256; o <<= 1) {
        int add = (t >= o) ? stmp[t - o] : 0;
        __syncthreads();
        stmp[t] += add;
        __syncthreads();
    }
    lofs[t] = stmp[t] - v;  // exclusive
    lcur[t] = 0;
    __syncthreads();
    int node = b * 256 + t;
    int cls = -1, r = 0;
    if (node < n) {
        deg[node] = v;
        offs[node] = gb + lofs[t];
        cls = (v <= 16) ? 0 : ((v <= 32) ? 1 : 2);
        r = atomicAdd(&lc[cls], 1);
    }
    __syncthreads();
    if (t < 3) lb[t] = lc[t] ? atomicAdd(&meta[t], lc[t]) : 0;
    __syncthreads();
    if (node < n) {
        int* nl = (cls == 0) ? nl0 : ((cls == 1) ? nl1 : nl2);
        nl[lb[cls] + r] = node;
    }
    for (int i = t; i < cnt; i += 256) {
        uint p = bd[i];
        int dl = p & 255;
        int rr = atomicAdd(&lcur[dl], 1);
        ssrc[gb + lofs[dl] + rr] = (int)(p >> 8);
    }
}

// ---------------------------------------------------------------------------
// Barrier-free MFMA GEMM: C[64 rows x 128 cols] = A[rows,K] * Wt^T.
// A/B fragments loaded directly from global (Wt is 32-64KB -> L1/L2-resident;
// A streamed once).  No LDS in the K-loop; one barrier for the epilogue.
// Verified fragment layouts: A[m=lane&15][k=quad*8+j]; B from Bt[n][k] rows;
// C/D col=lane&15, row=quad*4+reg.
// ---------------------------------------------------------------------------
template <int K, bool L2MODE, bool AFP32>
__global__ __launch_bounds__(256) void gemm_m(
    const float* __restrict__ Af, const ushort* __restrict__ Ab,
    const ushort* __restrict__ Wt, ushort* __restrict__ Hb,
    float* __restrict__ hres, int nrows,
    const float* __restrict__ al, const float* __restrict__ ar,
    float* __restrict__ el, float* __restrict__ er) {
    __shared__ float smem[64 * 132 + 256];
    float* Cs = smem;
    float* alr = smem + 64 * 132;
    const int tid = threadIdx.x;
    const int w = tid >> 6;
    const int lane = tid & 63;
    const int l15 = lane & 15, quad = lane >> 4;
    const int row0 = blockIdx.x * 64;
    constexpr int NC = L2MODE ? 64 : 128;

    if (tid < 2 * NC) alr[tid] = (tid < NC) ? al[tid] : ar[tid - NC];

    const int arow = row0 + w * 16 + l15;
    const bool aval = arow < nrows;

    f32x4 acc[8];
#pragma unroll
    for (int i = 0; i < 8; ++i) acc[i] = (f32x4){0.f, 0.f, 0.f, 0.f};

    union BC { uint4 u; bf16x8 b; };

#pragma unroll 1
    for (int kt = 0; kt < K / 64; ++kt) {
#pragma unroll
        for (int ks = 0; ks < 2; ++ks) {
            const int kc = kt * 64 + ks * 32 + quad * 8;
            bf16x8 af = {0, 0, 0, 0, 0, 0, 0, 0};
            if (AFP32) {
                if (aval) {
                    float4 v0 = *(const float4*)&Af[(size_t)arow * K + kc];
                    float4 v1 = *(const float4*)&Af[(size_t)arow * K + kc + 4];
                    BC cu; cu.u = pack8(v0, v1);
                    af = cu.b;
                }
            } else {
                if (aval) af = *(const bf16x8*)&Ab[(size_t)arow * K + kc];
            }
#pragma unroll
            for (int ct = 0; ct < 8; ++ct) {
                bf16x8 bf = *(const bf16x8*)&Wt[(size_t)(ct * 16 + l15) * K + kc];
                acc[ct] = __builtin_amdgcn_mfma_f32_16x16x32_bf16(af, bf, acc[ct], 0, 0, 0);
            }
        }
    }

    // ---- epilogue: C tile -> LDS (64 x 132 fp32) ----
#pragma unroll
    for (int ct = 0; ct < 8; ++ct)
#pragma unroll
        for (int r = 0; r < 4; ++r)
            Cs[(w * 16 + quad * 4 + r) * 132 + ct * 16 + l15] = acc[ct][r];
    __syncthreads();

    if (L2MODE) {
#pragma unroll
        for (int t = 0; t < 2; ++t) {
            int chunk = tid + t * 256;
            int r = chunk >> 3, c8 = chunk & 7;
            int grow = row0 + r;
            if (grow < nrows) {
                float4 v0 = *(float4*)&Cs[r * 132 + c8 * 8];
                float4 v1 = *(float4*)&Cs[r * 132 + c8 * 8 + 4];
                *(uint4*)&Hb[(size_t)grow * 64 + c8 * 8] = pack8(v0, v1);
            }
        }
#pragma unroll
        for (int t = 0; t < 4; ++t) {
            int chunk = tid + t * 256;
            int r = chunk >> 4, c4 = chunk & 15;
            int grow = row0 + r;
            if (grow < nrows)
                *(float4*)&hres[(size_t)grow * 64 + c4 * 4] =
                    *(float4*)&Cs[r * 132 + 64 + c4 * 4];
        }
    } else {
#pragma unroll
        for (int t = 0; t < 4; ++t) {
            int chunk = tid + t * 256;
            int r = chunk >> 4, c8 = chunk & 15;
            int grow = row0 + r;
            if (grow < nrows) {
                float4 v0 = *(float4*)&Cs[r * 132 + c8 * 8];
                float4 v1 = *(float4*)&Cs[r * 132 + c8 * 8 + 4];
                *(uint4*)&Hb[(size_t)grow * 128 + c8 * 8] = pack8(v0, v1);
            }
        }
    }
    // el/er: 64 rows x 2 heads x {el,er} = 256 threads
    {
        constexpr int HD = L2MODE ? 32 : 64;
        int r = tid >> 2, hh = (tid >> 1) & 1, iser = tid & 1;
        int grow = row0 + r;
        const float* coef = alr + iser * NC + hh * HD;
        const float* crow = Cs + r * 132 + hh * HD;
        float sum = 0.f;
#pragma unroll
        for (int i = 0; i < HD; ++i) sum += crow[i] * coef[i];
        if (grow < nrows) (iser ? er : el)[grow * 2 + hh] = sum;
    }
}

// ---------------------------------------------------------------------------
// Aggregation for one node handled by LPN lanes (group-aligned within wave).
// LPN=16: 4 nodes/wave (deg<=16).  LPN=32: 2 nodes/wave (deg<=32).
// LPN=64: full wave; also handles deg>64 via online pass.
// UB=8: eight uint4 gathers in flight per lane (latency hiding).
// ---------------------------------------------------------------------------
template <int D, bool MEAN_HEADS, bool RES_BF16, int LPN>
__device__ __forceinline__ void agg_group(
    int node, int lane, float2* __restrict__ wlsw,
    const int* __restrict__ ssrc, const int* __restrict__ offs,
    const int* __restrict__ deg, const ushort* __restrict__ hb,
    const float* __restrict__ el, const float* __restrict__ er,
    const float* __restrict__ bias, const void* __restrict__ res,
    float* __restrict__ out, ushort* __restrict__ outb, int act) {
    constexpr int F = 2 * D;       // feats per row
    constexpr int CH = F / 8;      // uint4 chunks per row
    constexpr int ESL = LPN / CH;  // edge slots in flight per group
    constexpr int UB = 8;          // batched slots
    static_assert(ESL >= 1, "LPN must cover a full row");
    const int g = lane / LPN, sl = lane % LPN;
    const bool valid = node >= 0;
    float2* wls = wlsw + g * (LPN * 2);  // group staging: LPN edges x 2 heads
    int off = 0, dg = 0;
    float2 ern = make_float2(0.f, 0.f);
    if (valid) {
        off = offs[node];
        dg = deg[node];
        ern = *(const float2*)&er[node * 2];
    }
    const uint4* __restrict__ hp = (const uint4*)hb;
    const int c = sl & (CH - 1);
    const int es = sl / CH;
    const int h1 = (c >= CH / 2) ? 1 : 0;
    const float2* wbase = wls + es * 2 + h1;
    float acc[8];
#pragma unroll
    for (int i = 0; i < 8; ++i) acc[i] = 0.f;

    auto inner = [&](int cnt) {
        for (int p = 0; p < cnt; p += UB * ESL) {
            float2 mw[UB];
#pragma unroll
            for (int u = 0; u < UB; ++u) mw[u] = wbase[(p + u * ESL) * 2];
            uint4 q[UB];
#pragma unroll
            for (int u = 0; u < UB; ++u)
                q[u] = hp[(size_t)__float_as_int(mw[u].x) * CH + c];
#pragma unroll
            for (int u = 0; u < UB; ++u) {
                float wj = mw[u].y;
                acc[0] += wj * __uint_as_float(q[u].x << 16);
                acc[1] += wj * __uint_as_float(q[u].x & 0xffff0000u);
                acc[2] += wj * __uint_as_float(q[u].y << 16);
                acc[3] += wj * __uint_as_float(q[u].y & 0xffff0000u);
                acc[4] += wj * __uint_as_float(q[u].z << 16);
                acc[5] += wj * __uint_as_float(q[u].z & 0xffff0000u);
                acc[6] += wj * __uint_as_float(q[u].w << 16);
                acc[7] += wj * __uint_as_float(q[u].w & 0xffff0000u);
            }
        }
    };

    bool big = false;
    if constexpr (LPN == 64) big = (dg > 64);

    if (!big) {  // dg <= LPN: single staged pass, butterfly softmax over LPN
        int sidx = 0;
        float a = -INFINITY, b = -INFINITY;
        if (valid && sl < dg) {
            sidx = ssrc[off + sl];
            float2 ev = *(const float2*)&el[sidx * 2];
            a = ev.x + ern.x; a = fmaxf(a, 0.2f * a);
            b = ev.y + ern.y; b = fmaxf(b, 0.2f * b);
        }
        float m0 = a, m1 = b;
#pragma unroll
        for (int o = LPN / 2; o; o >>= 1) {
            m0 = fmaxf(m0, __shfl_xor(m0, o));
            m1 = fmaxf(m1, __shfl_xor(m1, o));
        }
        float p0 = (valid && sl < dg) ? __expf(a - m0) : 0.f;
        float p1 = (valid && sl < dg) ? __expf(b - m1) : 0.f;
        float s0 = p0, s1 = p1;
#pragma unroll
        for (int o = LPN / 2; o; o >>= 1) {
            s0 += __shfl_xor(s0, o);
            s1 += __shfl_xor(s1, o);
        }
        float is0 = s0 > 0.f ? 1.f / s0 : 0.f;
        float is1 = s1 > 0.f ? 1.f / s1 : 0.f;
        wls[sl * 2 + 0] = make_float2(__int_as_float(sidx), p0 * is0);
        wls[sl * 2 + 1] = make_float2(__int_as_float(sidx), p1 * is1);
        inner(dg);
    } else if constexpr (LPN == 64) {  // rare: deg > 64, online (m, s) pass
        float s0 = 0.f, s1 = 0.f;
        float m0 = -INFINITY, m1 = -INFINITY;
        for (int k = sl; k < dg; k += 64) {
            int sidx = ssrc[off + k];
            float2 ev = *(const float2*)&el[sidx * 2];
            float a = ev.x + ern.x; a = fmaxf(a, 0.2f * a);
            float b = ev.y + ern.y; b = fmaxf(b, 0.2f * b);
            float nm = fmaxf(m0, a);
            s0 = s0 * __expf(m0 - nm) + __expf(a - nm); m0 = nm;
            nm = fmaxf(m1, b);
            s1 = s1 * __expf(m1 - nm) + __expf(b - nm); m1 = nm;
        }
        for (int o = 32; o; o >>= 1) {
            float om = __shfl_xor(m0, o), os = __shfl_xor(s0, o);
            float nm = fmaxf(m0, om);
            s0 = (nm == -INFINITY) ? 0.f : s0 * __expf(m0 - nm) + os * __expf(om - nm);
            m0 = nm;
            om = __shfl_xor(m1, o); os = __shfl_xor(s1, o);
            nm = fmaxf(m1, om);
            s1 = (nm == -INFINITY) ? 0.f : s1 * __expf(m1 - nm) + os * __expf(om - nm);
            m1 = nm;
        }
        float is0 = s0 > 0.f ? 1.f / s0 : 0.f;
        float is1 = s1 > 0.f ? 1.f / s1 : 0.f;
        for (int cc = 0; cc < dg; cc += 64) {
            int k = cc + sl;
            int sidx = 0;
            float w0 = 0.f, w1 = 0.f;
            if (k < dg) {
                sidx = ssrc[off + k];
                float2 ev = *(const float2*)&el[sidx * 2];
                float a = ev.x + ern.x; a = fmaxf(a, 0.2f * a);
                float b = ev.y + ern.y; b = fmaxf(b, 0.2f * b);
                w0 = __expf(a - m0) * is0;
                w1 = __expf(b - m1) * is1;
            }
            wls[sl * 2 + 0] = make_float2(__int_as_float(sidx), w0);
            wls[sl * 2 + 1] = make_float2(__int_as_float(sidx), w1);
            inner(min(64, dg - cc));
        }
    }

    // cross-slot reduce (within group); no-op when LPN == CH
#pragma unroll
    for (int o = CH; o < LPN; o <<= 1) {
#pragma unroll
        for (int i = 0; i < 8; ++i) acc[i] += __shfl_xor(acc[i], o);
    }
    if (!valid) return;

    const int f0 = c * 8;
    float4 b0v = *(const float4*)&bias[f0];
    float4 b1v = *(const float4*)&bias[f0 + 4];
    float vv[8] = {acc[0] + b0v.x, acc[1] + b0v.y, acc[2] + b0v.z, acc[3] + b0v.w,
                   acc[4] + b1v.x, acc[5] + b1v.y, acc[6] + b1v.z, acc[7] + b1v.w};
    if (res) {
        if (RES_BF16) {
            uint4 r = ((const uint4*)res)[(size_t)node * CH + c];
            vv[0] += __uint_as_float(r.x << 16);
            vv[1] += __uint_as_float(r.x & 0xffff0000u);
            vv[2] += __uint_as_float(r.y << 16);
            vv[3] += __uint_as_float(r.y & 0xffff0000u);
            vv[4] += __uint_as_float(r.z << 16);
            vv[5] += __uint_as_float(r.z & 0xffff0000u);
            vv[6] += __uint_as_float(r.w << 16);
            vv[7] += __uint_as_float(r.w & 0xffff0000u);
        } else {
            const float* rf = (const float*)res;
            float4 r0v = *(const float4*)&rf[(size_t)node * F + f0];
            float4 r1v = *(const float4*)&rf[(size_t)node * F + f0 + 4];
            vv[0] += r0v.x; vv[1] += r0v.y; vv[2] += r0v.z; vv[3] += r0v.w;
            vv[4] += r1v.x; vv[5] += r1v.y; vv[6] += r1v.z; vv[7] += r1v.w;
        }
    }
    if (act) {
#pragma unroll
        for (int i = 0; i < 8; ++i)
            vv[i] = vv[i] > 0.f ? vv[i] : __expf(vv[i]) - 1.f;
    }
    if (MEAN_HEADS) {
        float ov[8];
#pragma unroll
        for (int i = 0; i < 8; ++i) ov[i] = __shfl_xor(vv[i], CH / 2);
        if (es == 0 && c < CH / 2) {
            float4 u0 = make_float4(0.5f * (vv[0] + ov[0]), 0.5f * (vv[1] + ov[1]),
                                    0.5f * (vv[2] + ov[2]), 0.5f * (vv[3] + ov[3]));
            float4 u1 = make_float4(0.5f * (vv[4] + ov[4]), 0.5f * (vv[5] + ov[5]),
                                    0.5f * (vv[6] + ov[6]), 0.5f * (vv[7] + ov[7]));
            *(float4*)&out[(size_t)node * D + f0] = u0;
            *(float4*)&out[(size_t)node * D + f0 + 4] = u1;
        }
    } else if (es == 0) {
        if (out) {
            *(float4*)&out[(size_t)node * F + f0] =
                make_float4(vv[0], vv[1], vv[2], vv[3]);
            *(float4*)&out[(size_t)node * F + f0 + 4] =
                make_float4(vv[4], vv[5], vv[6], vv[7]);
        }
        if (outb) {
            *(uint4*)&outb[(size_t)node * F + f0] =
                pack8(make_float4(vv[0], vv[1], vv[2], vv[3]),
                      make_float4(vv[4], vv[5], vv[6], vv[7]));
        }
    }
}

// ---------------------------------------------------------------------------
// Degree-binned aggregation driver: grid-strides over flattened item space
// [class0 items (4 nodes) | class1 items (2 nodes) | class2 items (1 node)].
// Item-space bounds computed from raw class counts (meta[0..2]).
// ---------------------------------------------------------------------------
template <int D, bool MEAN_HEADS, bool RES_BF16>
__global__ __launch_bounds__(256) void agg_c2(
    const int* __restrict__ meta, const int* __restrict__ nl0,
    const int* __restrict__ nl1, const int* __restrict__ nl2,
    const int* __restrict__ ssrc, const int* __restrict__ offs,
    const int* __restrict__ deg, const ushort* __restrict__ hb,
    const float* __restrict__ el, const float* __restrict__ er,
    const float* __restrict__ bias, const void* __restrict__ res,
    float* __restrict__ out, ushort* __restrict__ outb, int act) {
    __shared__ float2 wls_all[4][128];   // per-wave staging
    const int wid = threadIdx.x >> 6;
    const int lane = threadIdx.x & 63;
    float2* wls = wls_all[wid];
    const int c0 = meta[0], c1 = meta[1], c2 = meta[2];
    const int I0 = (c0 + 3) >> 2;
    const int I01 = I0 + ((c1 + 1) >> 1);
    const int T = I01 + c2;
    const int nW = gridDim.x * 4;
    for (int it = blockIdx.x * 4 + wid; it < T; it += nW) {
        if (it < I0) {
            int idx = it * 4 + (lane >> 4);
            int node = (idx < c0) ? nl0[idx] : -1;
            agg_group<D, MEAN_HEADS, RES_BF16, 16>(node, lane, wls, ssrc, offs,
                                                   deg, hb, el, er, bias, res,
                                                   out, outb, act);
        } else if (it < I01) {
            int idx = (it - I0) * 2 + (lane >> 5);
            int node = (idx < c1) ? nl1[idx] : -1;
            agg_group<D, MEAN_HEADS, RES_BF16, 32>(node, lane, wls, ssrc, offs,
                                                   deg, hb, el, er, bias, res,
                                                   out, outb, act);
        } else {
            int node = nl2[it - I01];
            agg_group<D, MEAN_HEADS, RES_BF16, 64>(node, lane, wls, ssrc, offs,
                                                   deg, hb, el, er, bias, res,
                                                   out, outb, act);
        }
    }
}

// ---------------------------------------------------------------------------

extern "C" void kernel_launch(void* const* d_in, const int* in_sizes, int n_in,
                              void* d_out, int out_size, void* d_ws, size_t ws_size,
                              hipStream_t stream) {
    const float* x     = (const float*)d_in[0];
    const int*   esrc  = (const int*)d_in[1];
    const int*   edst  = (const int*)d_in[2];
    const float* W0    = (const float*)d_in[3];
    const float* al0   = (const float*)d_in[4];
    const float* ar0   = (const float*)d_in[5];
    const float* b0    = (const float*)d_in[6];
    const float* W1    = (const float*)d_in[7];
    const float* al1   = (const float*)d_in[8];
    const float* ar1   = (const float*)d_in[9];
    const float* b1    = (const float*)d_in[10];
    const float* W2    = (const float*)d_in[11];
    const float* al2   = (const float*)d_in[12];
    const float* ar2   = (const float*)d_in[13];
    const float* b2    = (const float*)d_in[14];
    const float* Wres2 = (const float*)d_in[15];

    const int N = in_sizes[0] / 256;  // 50000
    const int E = in_sizes[1];        // 800000

    // workspace layout
    float* ws = (float*)d_ws;
    float* hres  = ws;                      // [N,64]  L2 projected residual
    float* el    = hres + (size_t)N * 64;   // [N,2]
    float* er    = el + (size_t)N * 2;      // [N,2]
    int* deg     = (int*)(er + (size_t)N * 2);
    int* offs    = deg + N;
    int* bcur    = offs + N;                // [256] (196 used; meta at +208)
    int* bbase   = bcur + 256;              // [256] (unused; layout keep)
    int* ssrc    = bbase + 256;             // [E]
    uint* bdata  = (uint*)(ssrc + E);       // [NBK * BCAP]
    ushort* Hb   = (ushort*)(bdata + (size_t)NBK * BCAP);  // [N,128] bf16
    ushort* Ab   = Hb + (size_t)N * 128;    // [N,128] bf16 agg0 out
    ushort* Bb   = Ab + (size_t)N * 128;    // [N,128] bf16 agg1 out
    ushort* Wt0  = Bb + (size_t)N * 128;    // [128,256] bf16 W0^T
    ushort* Wt1  = Wt0 + 128 * 256;         // [128,128] bf16 W1^T
    ushort* Wt2c = Wt1 + 128 * 128;         // [128,128] bf16 [W2|Wres2]^T
    int* nl0     = (int*)(Wt2c + 128 * 128);  // [N] deg<=16
    int* nl1     = nl0 + N;                 // [N] 17..32
    int* nl2     = nl1 + N;                 // [N] >32
    int* meta    = bcur + 208;              // [3] class counts (memset w/ bcur)

    // ---- bucket-CSR build + weight prep (fused) ----
    hipMemsetAsync(bcur, 0, 256 * sizeof(int), stream);
    const int nba = (E + 2047) / 2048;  // 391
    buildA_k<<<nba + 256, 256, 0, stream>>>(esrc, edst, E, bcur, bdata, nba,
                                            W0, W1, W2, Wres2, Wt0, Wt1, Wt2c);
    bucketB_k<<<NBK, 256, 0, stream>>>(bdata, bcur, deg, offs, ssrc, N,
                                       meta, nl0, nl1, nl2);

    int gblk = (N + 63) / 64;  // 782
    const int ablk = 2048;     // 8192 waves, grid-stride over items

    // ---- Layer 0: IN=256 -> [N,2,64], ELU ----
    gemm_m<256, false, true><<<gblk, 256, 0, stream>>>(
        x, nullptr, Wt0, Hb, nullptr, N, al0, ar0, el, er);
    agg_c2<64, false, false><<<ablk, 256, 0, stream>>>(
        meta, nl0, nl1, nl2, ssrc, offs, deg, Hb, el, er, b0, nullptr,
        nullptr, Ab, 1);

    // ---- Layer 1: 128 -> [N,2,64], identity residual (Ab, bf16), ELU ----
    gemm_m<128, false, false><<<gblk, 256, 0, stream>>>(
        nullptr, Ab, Wt1, Hb, nullptr, N, al1, ar1, el, er);
    agg_c2<64, false, true><<<ablk, 256, 0, stream>>>(
        meta, nl0, nl1, nl2, ssrc, offs, deg, Hb, el, er, b1, Ab,
        nullptr, Bb, 1);

    // ---- Layer 2: 128 -> [N,2,32], W2+Wres2 fused, head-mean ----
    gemm_m<128, true, false><<<gblk, 256, 0, stream>>>(
        nullptr, Bb, Wt2c, Hb, hres, N, al2, ar2, el, er);
    agg_c2<32, true, false><<<ablk, 256, 0, stream>>>(
        meta, nl0, nl1, nl2, ssrc, offs, deg, Hb, el, er, b2, hres,
        (float*)d_out, nullptr, 0);
}

// Round 4
// 274.163 us; speedup vs baseline: 1.1476x; 1.1476x over previous
//
#include <hip/hip_runtime.h>
#include <math.h>

// ---------------------------------------------------------------------------
// GAT, 3 layers, N=50000, E=800000, H=2 heads, D=64/64/32.
// Bucket-CSR build (2-pass, locality-aware); LDS-staged bf16 MFMA GEMM
// (16x16x32, 128x128 tile, 32 rows/wave for B-frag reuse) with fused el/er +
// bf16-h epilogue; bucketB hidden under gemm0 (fused dispatch);
// degree-binned aggregation (16/32/64 lanes per node), UB=8 gather batching.
// ---------------------------------------------------------------------------

typedef unsigned int uint;
typedef unsigned short ushort;
typedef __attribute__((ext_vector_type(8))) short bf16x8;
typedef __attribute__((ext_vector_type(4))) float f32x4;

#define NBK 196     // buckets = ceil(50000/256); bucket = dst >> 8
#define BCAP 4608   // per-bucket capacity (mean 4082, sigma 64 -> +8 sigma)

__device__ inline uint f2bf(float f) {  // fp32 -> bf16 bits, RNE
    uint u = __float_as_uint(f);
    return (u + 0x7fffu + ((u >> 16) & 1u)) >> 16;
}

__device__ inline uint4 pack8(float4 a, float4 b) {
    return make_uint4(f2bf(a.x) | (f2bf(a.y) << 16), f2bf(a.z) | (f2bf(a.w) << 16),
                      f2bf(b.x) | (f2bf(b.y) << 16), f2bf(b.z) | (f2bf(b.w) << 16));
}

// ---------------------------------------------------------------------------
// Fused pass: blocks [0, nba) = bucketA (edges -> per-bucket append regions);
// blocks [nba, nba+256) = weight transpose+bf16 (independent inputs).
// ---------------------------------------------------------------------------
__global__ __launch_bounds__(256) void buildA_k(
    const int* __restrict__ src, const int* __restrict__ dst, int E,
    int* __restrict__ bcur, uint* __restrict__ bdata, int nba,
    const float* __restrict__ W0, const float* __restrict__ W1,
    const float* __restrict__ W2, const float* __restrict__ Wr,
    ushort* __restrict__ Wt0, ushort* __restrict__ Wt1,
    ushort* __restrict__ Wt2cat) {
    __shared__ int lhist[NBK];
    __shared__ int gbase[NBK];
    const int t = threadIdx.x;
    if ((int)blockIdx.x >= nba) {      // ---- weight-prep blocks ----
        int wb = blockIdx.x - nba;
        if (wb < 128) {                // W0: 32768 elems
            int i = wb * 256 + t;
            int n = i >> 8, k = i & 255;
            Wt0[n * 256 + k] = (ushort)f2bf(W0[k * 128 + n]);
        } else if (wb < 192) {         // W1: 16384
            int i = (wb - 128) * 256 + t;
            int n = i >> 7, k = i & 127;
            Wt1[n * 128 + k] = (ushort)f2bf(W1[k * 128 + n]);
        } else if (wb < 224) {         // W2: 8192
            int i = (wb - 192) * 256 + t;
            int n = i >> 7, k = i & 127;
            Wt2cat[n * 128 + k] = (ushort)f2bf(W2[k * 64 + n]);
        } else {                       // Wres2: 8192
            int i = (wb - 224) * 256 + t;
            int n = i >> 7, k = i & 127;
            Wt2cat[(64 + n) * 128 + k] = (ushort)f2bf(Wr[k * 64 + n]);
        }
        return;
    }
    // ---- bucketA blocks ----
    for (int i = t; i < NBK; i += 256) lhist[i] = 0;
    __syncthreads();
    const int e0 = blockIdx.x * 2048 + t * 8;
    uint payload[8], meta[8];
#pragma unroll
    for (int i = 0; i < 8; ++i) {
        int e = e0 + i;
        if (e < E) {
            int s = src[e], d = dst[e];
            int b = d >> 8;
            int r = atomicAdd(&lhist[b], 1);
            payload[i] = ((uint)s << 8) | (uint)(d & 255);
            meta[i] = ((uint)b << 16) | (uint)r;
        } else {
            meta[i] = 0xffffffffu;
        }
    }
    __syncthreads();
    for (int i = t; i < NBK; i += 256) {
        int c = lhist[i];
        gbase[i] = c ? atomicAdd(&bcur[i], c) : 0;
    }
    __syncthreads();
#pragma unroll
    for (int i = 0; i < 8; ++i) {
        if (meta[i] != 0xffffffffu) {
            int b = meta[i] >> 16;
            int pos = gbase[b] + (int)(meta[i] & 0xffffu);
            if (pos < BCAP) bdata[(size_t)b * BCAP + pos] = payload[i];
        }
    }
}

// ---------------------------------------------------------------------------
// Bucket pass B body (+ inline 196-bucket prefix scan + degree binning).
// One block per bucket -> deg/offs/ssrc (CSR) + class lists nl0/nl1/nl2.
// LDS carved from caller's smem (overlaid with gemm smem in fused kernel).
// ---------------------------------------------------------------------------
__device__ void bucketB_body(
    float* smemf, int b, const uint* __restrict__ bdata,
    const int* __restrict__ bcur, int* __restrict__ deg,
    int* __restrict__ offs, int* __restrict__ ssrc, int n,
    int* __restrict__ meta, int* __restrict__ nl0, int* __restrict__ nl1,
    int* __restrict__ nl2) {
    int* lhist = (int*)smemf;        // 256
    int* lofs  = lhist + 256;        // 256
    int* lcur  = lofs + 256;         // 256
    int* stmp  = lcur + 256;         // 256
    int* lc    = stmp + 256;         // 3
    int* lb    = lc + 3;             // 3
    int* sgb   = lb + 3;             // 1
    const int t = threadIdx.x;
    const int cnt = min(bcur[b], BCAP);
    // inline exclusive prefix over the 196 bucket counts -> this bucket's base
    int cv = (t < NBK) ? min(bcur[t], BCAP) : 0;
    stmp[t] = cv;
    lhist[t] = 0;
    if (t < 3) lc[t] = 0;
    __syncthreads();
    for (int o = 1; o < 256; o <<= 1) {
        int add = (t >= o) ? stmp[t - o] : 0;
        __syncthreads();
        stmp[t] += add;
        __syncthreads();
    }
    if (t == 0) sgb[0] = b ? stmp[b - 1] : 0;
    __syncthreads();
    const int gb = sgb[0];
    const uint* bd = bdata + (size_t)b * BCAP;
    for (int i = t; i < cnt; i += 256)
        atomicAdd(&lhist[bd[i] & 255], 1);
    __syncthreads();
    int v = lhist[t];
    stmp[t] = v;
    __syncthreads();
    for (int o = 1; o < 256; o <<= 1) {
        int add = (t >= o) ? stmp[t - o] : 0;
        __syncthreads();
        stmp[t] += add;
        __syncthreads();
    }
    lofs[t] = stmp[t] - v;  // exclusive
    lcur[t] = 0;
    __syncthreads();
    int node = b * 256 + t;
    int cls = -1, r = 0;
    if (node < n) {
        deg[node] = v;
        offs[node] = gb + lofs[t];
        cls = (v <= 16) ? 0 : ((v <= 32) ? 1 : 2);
        r = atomicAdd(&lc[cls], 1);
    }
    __syncthreads();
    if (t < 3) lb[t] = lc[t] ? atomicAdd(&meta[t], lc[t]) : 0;
    __syncthreads();
    if (node < n) {
        int* nl = (cls == 0) ? nl0 : ((cls == 1) ? nl1 : nl2);
        nl[lb[cls] + r] = node;
    }
    for (int i = t; i < cnt; i += 256) {
        uint p = bd[i];
        int dl = p & 255;
        int rr = atomicAdd(&lcur[dl], 1);
        ssrc[gb + lofs[dl] + rr] = (int)(p >> 8);
    }
}

// ---------------------------------------------------------------------------
// MFMA GEMM body: C[128 rows x 128 cols] = A[rows,K] * Wt^T.  BK=64, 4 waves,
// each wave 32 rows x 128 cols (acc[2][8]) so each B-frag read feeds 2 MFMA
// (20 ds_read_b128 per 32 MFMA).  Epilogue in two 64-row halves via LDS.
// Verified fragment layouts: A[m=lane&15][k=quad*8+j]; B from Bt[n][k] rows;
// C/D col=lane&15, row=quad*4+reg.
// ---------------------------------------------------------------------------
template <int K, bool L2MODE, bool AFP32>
__device__ void gemm_body(
    float* smem, const float* __restrict__ Af, const ushort* __restrict__ Ab,
    const ushort* __restrict__ Wt, ushort* __restrict__ Hb,
    float* __restrict__ hres, int nrows,
    const float* __restrict__ al, const float* __restrict__ ar,
    float* __restrict__ el, float* __restrict__ er, int bid) {
    constexpr int AS = 72;                    // LDS row stride in bf16
    ushort* As = (ushort*)smem;               // 128 x 72 bf16
    ushort* Ws = (ushort*)smem + 128 * AS;    // 128 x 72 bf16
    float* Cs = smem;                         // 64 x 132 fp32 (epilogue)
    float* alr = smem + 9216;                 // staged al|ar (256 floats)
    const int tid = threadIdx.x;
    const int w = tid >> 6;
    const int lane = tid & 63;
    const int l15 = lane & 15, quad = lane >> 4;
    const int row0 = bid * 128;
    constexpr int NC = L2MODE ? 64 : 128;

    if (tid < 2 * NC) alr[tid] = (tid < NC) ? al[tid] : ar[tid - NC];

    f32x4 acc[2][8];
#pragma unroll
    for (int m = 0; m < 2; ++m)
#pragma unroll
        for (int i = 0; i < 8; ++i) acc[m][i] = (f32x4){0.f, 0.f, 0.f, 0.f};

    for (int kt = 0; kt < K / 64; ++kt) {
        const int k0 = kt * 64;
        if (AFP32) {
#pragma unroll
            for (int t = 0; t < 8; ++t) {
                int idx = tid + t * 256;
                int r = idx >> 4, c4 = idx & 15;
                float4 v = make_float4(0.f, 0.f, 0.f, 0.f);
                if (row0 + r < nrows)
                    v = *(const float4*)&Af[(size_t)(row0 + r) * K + k0 + c4 * 4];
                ushort4 o;
                o.x = (ushort)f2bf(v.x); o.y = (ushort)f2bf(v.y);
                o.z = (ushort)f2bf(v.z); o.w = (ushort)f2bf(v.w);
                *(ushort4*)&As[r * AS + c4 * 4] = o;
            }
        } else {
#pragma unroll
            for (int t = 0; t < 4; ++t) {
                int idx = tid + t * 256;
                int r = idx >> 3, c8 = idx & 7;
                uint4 v = make_uint4(0, 0, 0, 0);
                if (row0 + r < nrows)
                    v = *(const uint4*)&Ab[(size_t)(row0 + r) * K + k0 + c8 * 8];
                *(uint4*)&As[r * AS + c8 * 8] = v;
            }
        }
#pragma unroll
        for (int t = 0; t < 4; ++t) {
            int idx = tid + t * 256;
            int n = idx >> 3, c8 = idx & 7;
            *(uint4*)&Ws[n * AS + c8 * 8] =
                *(const uint4*)&Wt[(size_t)n * K + k0 + c8 * 8];
        }
        __syncthreads();
#pragma unroll
        for (int ks = 0; ks < 2; ++ks) {
            bf16x8 a0 = *(const bf16x8*)&As[(w * 32 + l15) * AS + ks * 32 + quad * 8];
            bf16x8 a1 = *(const bf16x8*)&As[(w * 32 + 16 + l15) * AS + ks * 32 + quad * 8];
#pragma unroll
            for (int ct = 0; ct < 8; ++ct) {
                bf16x8 bf = *(const bf16x8*)&Ws[(ct * 16 + l15) * AS + ks * 32 + quad * 8];
                acc[0][ct] = __builtin_amdgcn_mfma_f32_16x16x32_bf16(a0, bf, acc[0][ct], 0, 0, 0);
                acc[1][ct] = __builtin_amdgcn_mfma_f32_16x16x32_bf16(a1, bf, acc[1][ct], 0, 0, 0);
            }
        }
        __syncthreads();
    }

    // ---- epilogue: two 64-row halves through Cs (64 x 132 fp32) ----
#pragma unroll
    for (int h = 0; h < 2; ++h) {
        if ((w >> 1) == h) {
            int wl = w & 1;
#pragma unroll
            for (int m = 0; m < 2; ++m)
#pragma unroll
                for (int ct = 0; ct < 8; ++ct)
#pragma unroll
                    for (int r = 0; r < 4; ++r)
                        Cs[(wl * 32 + m * 16 + quad * 4 + r) * 132 + ct * 16 + l15] =
                            acc[m][ct][r];
        }
        __syncthreads();
        const int rbase = row0 + h * 64;
        if (L2MODE) {
#pragma unroll
            for (int t = 0; t < 2; ++t) {
                int chunk = tid + t * 256;
                int r = chunk >> 3, c8 = chunk & 7;
                int grow = rbase + r;
                if (grow < nrows) {
                    float4 v0 = *(float4*)&Cs[r * 132 + c8 * 8];
                    float4 v1 = *(float4*)&Cs[r * 132 + c8 * 8 + 4];
                    *(uint4*)&Hb[(size_t)grow * 64 + c8 * 8] = pack8(v0, v1);
                }
            }
#pragma unroll
            for (int t = 0; t < 4; ++t) {
                int chunk = tid + t * 256;
                int r = chunk >> 4, c4 = chunk & 15;
                int grow = rbase + r;
                if (grow < nrows)
                    *(float4*)&hres[(size_t)grow * 64 + c4 * 4] =
                        *(float4*)&Cs[r * 132 + 64 + c4 * 4];
            }
        } else {
#pragma unroll
            for (int t = 0; t < 4; ++t) {
                int chunk = tid + t * 256;
                int r = chunk >> 4, c8 = chunk & 15;
                int grow = rbase + r;
                if (grow < nrows) {
                    float4 v0 = *(float4*)&Cs[r * 132 + c8 * 8];
                    float4 v1 = *(float4*)&Cs[r * 132 + c8 * 8 + 4];
                    *(uint4*)&Hb[(size_t)grow * 128 + c8 * 8] = pack8(v0, v1);
                }
            }
        }
        // el/er: 64 rows x 2 heads x {el,er} = 256 threads
        {
            constexpr int HD = L2MODE ? 32 : 64;
            int r = tid >> 2, hh = (tid >> 1) & 1, iser = tid & 1;
            int grow = rbase + r;
            const float* coef = alr + iser * NC + hh * HD;
            const float* crow = Cs + r * 132 + hh * HD;
            float sum = 0.f;
#pragma unroll
            for (int i = 0; i < HD; ++i) sum += crow[i] * coef[i];
            if (grow < nrows) (iser ? er : el)[grow * 2 + hh] = sum;
        }
        __syncthreads();
    }
}

// standalone GEMM kernel (layers 1, 2)
template <int K, bool L2MODE, bool AFP32>
__global__ __launch_bounds__(256) void gemm_m(
    const float* __restrict__ Af, const ushort* __restrict__ Ab,
    const ushort* __restrict__ Wt, ushort* __restrict__ Hb,
    float* __restrict__ hres, int nrows,
    const float* __restrict__ al, const float* __restrict__ ar,
    float* __restrict__ el, float* __restrict__ er) {
    __shared__ float smem[9472];
    gemm_body<K, L2MODE, AFP32>(smem, Af, Ab, Wt, Hb, hres, nrows, al, ar,
                                el, er, blockIdx.x);
}

// fused: blocks [0, gblk) = gemm0 (x * W0); blocks [gblk, gblk+NBK) = bucketB
__global__ __launch_bounds__(256) void gemm0_bucketB_k(
    const float* __restrict__ x, const ushort* __restrict__ Wt0,
    ushort* __restrict__ Hb, int nrows,
    const float* __restrict__ al, const float* __restrict__ ar,
    float* __restrict__ el, float* __restrict__ er, int gblk,
    const uint* __restrict__ bdata, const int* __restrict__ bcur,
    int* __restrict__ deg, int* __restrict__ offs, int* __restrict__ ssrc,
    int* __restrict__ meta, int* __restrict__ nl0, int* __restrict__ nl1,
    int* __restrict__ nl2) {
    __shared__ float smem[9472];
    if ((int)blockIdx.x < gblk) {
        gemm_body<256, false, true>(smem, x, nullptr, Wt0, Hb, nullptr, nrows,
                                    al, ar, el, er, blockIdx.x);
    } else {
        bucketB_body(smem, blockIdx.x - gblk, bdata, bcur, deg, offs, ssrc,
                     nrows, meta, nl0, nl1, nl2);
    }
}

// ---------------------------------------------------------------------------
// Aggregation for one node handled by LPN lanes (group-aligned within wave).
// LPN=16: 4 nodes/wave (deg<=16).  LPN=32: 2 nodes/wave (deg<=32).
// LPN=64: full wave; also handles deg>64 via online pass.
// UB=8: eight uint4 gathers in flight per lane (latency hiding).
// ---------------------------------------------------------------------------
template <int D, bool MEAN_HEADS, bool RES_BF16, int LPN>
__device__ __forceinline__ void agg_group(
    int node, int lane, float2* __restrict__ wlsw,
    const int* __restrict__ ssrc, const int* __restrict__ offs,
    const int* __restrict__ deg, const ushort* __restrict__ hb,
    const float* __restrict__ el, const float* __restrict__ er,
    const float* __restrict__ bias, const void* __restrict__ res,
    float* __restrict__ out, ushort* __restrict__ outb, int act) {
    constexpr int F = 2 * D;       // feats per row
    constexpr int CH = F / 8;      // uint4 chunks per row
    constexpr int ESL = LPN / CH;  // edge slots in flight per group
    constexpr int UB = 8;          // batched slots
    static_assert(ESL >= 1, "LPN must cover a full row");
    const int g = lane / LPN, sl = lane % LPN;
    const bool valid = node >= 0;
    float2* wls = wlsw + g * (LPN * 2);  // group staging: LPN edges x 2 heads
    int off = 0, dg = 0;
    float2 ern = make_float2(0.f, 0.f);
    if (valid) {
        off = offs[node];
        dg = deg[node];
        ern = *(const float2*)&er[node * 2];
    }
    const uint4* __restrict__ hp = (const uint4*)hb;
    const int c = sl & (CH - 1);
    const int es = sl / CH;
    const int h1 = (c >= CH / 2) ? 1 : 0;
    const float2* wbase = wls + es * 2 + h1;
    float acc[8];
#pragma unroll
    for (int i = 0; i < 8; ++i) acc[i] = 0.f;

    auto inner = [&](int cnt) {
        for (int p = 0; p < cnt; p += UB * ESL) {
            float2 mw[UB];
#pragma unroll
            for (int u = 0; u < UB; ++u) mw[u] = wbase[(p + u * ESL) * 2];
            uint4 q[UB];
#pragma unroll
            for (int u = 0; u < UB; ++u)
                q[u] = hp[(size_t)__float_as_int(mw[u].x) * CH + c];
#pragma unroll
            for (int u = 0; u < UB; ++u) {
                float wj = mw[u].y;
                acc[0] += wj * __uint_as_float(q[u].x << 16);
                acc[1] += wj * __uint_as_float(q[u].x & 0xffff0000u);
                acc[2] += wj * __uint_as_float(q[u].y << 16);
                acc[3] += wj * __uint_as_float(q[u].y & 0xffff0000u);
                acc[4] += wj * __uint_as_float(q[u].z << 16);
                acc[5] += wj * __uint_as_float(q[u].z & 0xffff0000u);
                acc[6] += wj * __uint_as_float(q[u].w << 16);
                acc[7] += wj * __uint_as_float(q[u].w & 0xffff0000u);
            }
        }
    };

    bool big = false;
    if constexpr (LPN == 64) big = (dg > 64);

    if (!big) {  // dg <= LPN: single staged pass, butterfly softmax over LPN
        int sidx = 0;
        float a = -INFINITY, b = -INFINITY;
        if (valid && sl < dg) {
            sidx = ssrc[off + sl];
            float2 ev = *(const float2*)&el[sidx * 2];
            a = ev.x + ern.x; a = fmaxf(a, 0.2f * a);
            b = ev.y + ern.y; b = fmaxf(b, 0.2f * b);
        }
        float m0 = a, m1 = b;
#pragma unroll
        for (int o = LPN / 2; o; o >>= 1) {
            m0 = fmaxf(m0, __shfl_xor(m0, o));
            m1 = fmaxf(m1, __shfl_xor(m1, o));
        }
        float p0 = (valid && sl < dg) ? __expf(a - m0) : 0.f;
        float p1 = (valid && sl < dg) ? __expf(b - m1) : 0.f;
        float s0 = p0, s1 = p1;
#pragma unroll
        for (int o = LPN / 2; o; o >>= 1) {
            s0 += __shfl_xor(s0, o);
            s1 += __shfl_xor(s1, o);
        }
        float is0 = s0 > 0.f ? 1.f / s0 : 0.f;
        float is1 = s1 > 0.f ? 1.f / s1 : 0.f;
        wls[sl * 2 + 0] = make_float2(__int_as_float(sidx), p0 * is0);
        wls[sl * 2 + 1] = make_float2(__int_as_float(sidx), p1 * is1);
        inner(dg);
    } else if constexpr (LPN == 64) {  // rare: deg > 64, online (m, s) pass
        float s0 = 0.f, s1 = 0.f;
        float m0 = -INFINITY, m1 = -INFINITY;
        for (int k = sl; k < dg; k += 64) {
            int sidx = ssrc[off + k];
            float2 ev = *(const float2*)&el[sidx * 2];
            float a = ev.x + ern.x; a = fmaxf(a, 0.2f * a);
            float b = ev.y + ern.y; b = fmaxf(b, 0.2f * b);
            float nm = fmaxf(m0, a);
            s0 = s0 * __expf(m0 - nm) + __expf(a - nm); m0 = nm;
            nm = fmaxf(m1, b);
            s1 = s1 * __expf(m1 - nm) + __expf(b - nm); m1 = nm;
        }
        for (int o = 32; o; o >>= 1) {
            float om = __shfl_xor(m0, o), os = __shfl_xor(s0, o);
            float nm = fmaxf(m0, om);
            s0 = (nm == -INFINITY) ? 0.f : s0 * __expf(m0 - nm) + os * __expf(om - nm);
            m0 = nm;
            om = __shfl_xor(m1, o); os = __shfl_xor(s1, o);
            nm = fmaxf(m1, om);
            s1 = (nm == -INFINITY) ? 0.f : s1 * __expf(m1 - nm) + os * __expf(om - nm);
            m1 = nm;
        }
        float is0 = s0 > 0.f ? 1.f / s0 : 0.f;
        float is1 = s1 > 0.f ? 1.f / s1 : 0.f;
        for (int cc = 0; cc < dg; cc += 64) {
            int k = cc + sl;
            int sidx = 0;
            float w0 = 0.f, w1 = 0.f;
            if (k < dg) {
                sidx = ssrc[off + k];
                float2 ev = *(const float2*)&el[sidx * 2];
                float a = ev.x + ern.x; a = fmaxf(a, 0.2f * a);
                float b = ev.y + ern.y; b = fmaxf(b, 0.2f * b);
                w0 = __expf(a - m0) * is0;
                w1 = __expf(b - m1) * is1;
            }
            wls[sl * 2 + 0] = make_float2(__int_as_float(sidx), w0);
            wls[sl * 2 + 1] = make_float2(__int_as_float(sidx), w1);
            inner(min(64, dg - cc));
        }
    }

    // cross-slot reduce (within group); no-op when LPN == CH
#pragma unroll
    for (int o = CH; o < LPN; o <<= 1) {
#pragma unroll
        for (int i = 0; i < 8; ++i) acc[i] += __shfl_xor(acc[i], o);
    }
    if (!valid) return;

    const int f0 = c * 8;
    float4 b0v = *(const float4*)&bias[f0];
    float4 b1v = *(const float4*)&bias[f0 + 4];
    float vv[8] = {acc[0] + b0v.x, acc[1] + b0v.y, acc[2] + b0v.z, acc[3] + b0v.w,
                   acc[4] + b1v.x, acc[5] + b1v.y, acc[6] + b1v.z, acc[7] + b1v.w};
    if (res) {
        if (RES_BF16) {
            uint4 r = ((const uint4*)res)[(size_t)node * CH + c];
            vv[0] += __uint_as_float(r.x << 16);
            vv[1] += __uint_as_float(r.x & 0xffff0000u);
            vv[2] += __uint_as_float(r.y << 16);
            vv[3] += __uint_as_float(r.y & 0xffff0000u);
            vv[4] += __uint_as_float(r.z << 16);
            vv[5] += __uint_as_float(r.z & 0xffff0000u);
            vv[6] += __uint_as_float(r.w << 16);
            vv[7] += __uint_as_float(r.w & 0xffff0000u);
        } else {
            const float* rf = (const float*)res;
            float4 r0v = *(const float4*)&rf[(size_t)node * F + f0];
            float4 r1v = *(const float4*)&rf[(size_t)node * F + f0 + 4];
            vv[0] += r0v.x; vv[1] += r0v.y; vv[2] += r0v.z; vv[3] += r0v.w;
            vv[4] += r1v.x; vv[5] += r1v.y; vv[6] += r1v.z; vv[7] += r1v.w;
        }
    }
    if (act) {
#pragma unroll
        for (int i = 0; i < 8; ++i)
            vv[i] = vv[i] > 0.f ? vv[i] : __expf(vv[i]) - 1.f;
    }
    if (MEAN_HEADS) {
        float ov[8];
#pragma unroll
        for (int i = 0; i < 8; ++i) ov[i] = __shfl_xor(vv[i], CH / 2);
        if (es == 0 && c < CH / 2) {
            float4 u0 = make_float4(0.5f * (vv[0] + ov[0]), 0.5f * (vv[1] + ov[1]),
                                    0.5f * (vv[2] + ov[2]), 0.5f * (vv[3] + ov[3]));
            float4 u1 = make_float4(0.5f * (vv[4] + ov[4]), 0.5f * (vv[5] + ov[5]),
                                    0.5f * (vv[6] + ov[6]), 0.5f * (vv[7] + ov[7]));
            *(float4*)&out[(size_t)node * D + f0] = u0;
            *(float4*)&out[(size_t)node * D + f0 + 4] = u1;
        }
    } else if (es == 0) {
        if (out) {
            *(float4*)&out[(size_t)node * F + f0] =
                make_float4(vv[0], vv[1], vv[2], vv[3]);
            *(float4*)&out[(size_t)node * F + f0 + 4] =
                make_float4(vv[4], vv[5], vv[6], vv[7]);
        }
        if (outb) {
            *(uint4*)&outb[(size_t)node * F + f0] =
                pack8(make_float4(vv[0], vv[1], vv[2], vv[3]),
                      make_float4(vv[4], vv[5], vv[6], vv[7]));
        }
    }
}

// ---------------------------------------------------------------------------
// Degree-binned aggregation driver: grid-strides over flattened item space
// [class0 items (4 nodes) | class1 items (2 nodes) | class2 items (1 node)].
// Item-space bounds computed from raw class counts (meta[0..2]).
// ---------------------------------------------------------------------------
template <int D, bool MEAN_HEADS, bool RES_BF16>
__global__ __launch_bounds__(256) void agg_c2(
    const int* __restrict__ meta, const int* __restrict__ nl0,
    const int* __restrict__ nl1, const int* __restrict__ nl2,
    const int* __restrict__ ssrc, const int* __restrict__ offs,
    const int* __restrict__ deg, const ushort* __restrict__ hb,
    const float* __restrict__ el, const float* __restrict__ er,
    const float* __restrict__ bias, const void* __restrict__ res,
    float* __restrict__ out, ushort* __restrict__ outb, int act) {
    __shared__ float2 wls_all[4][128];   // per-wave staging
    const int wid = threadIdx.x >> 6;
    const int lane = threadIdx.x & 63;
    float2* wls = wls_all[wid];
    const int c0 = meta[0], c1 = meta[1], c2 = meta[2];
    const int I0 = (c0 + 3) >> 2;
    const int I01 = I0 + ((c1 + 1) >> 1);
    const int T = I01 + c2;
    const int nW = gridDim.x * 4;
    for (int it = blockIdx.x * 4 + wid; it < T; it += nW) {
        if (it < I0) {
            int idx = it * 4 + (lane >> 4);
            int node = (idx < c0) ? nl0[idx] : -1;
            agg_group<D, MEAN_HEADS, RES_BF16, 16>(node, lane, wls, ssrc, offs,
                                                   deg, hb, el, er, bias, res,
                                                   out, outb, act);
        } else if (it < I01) {
            int idx = (it - I0) * 2 + (lane >> 5);
            int node = (idx < c1) ? nl1[idx] : -1;
            agg_group<D, MEAN_HEADS, RES_BF16, 32>(node, lane, wls, ssrc, offs,
                                                   deg, hb, el, er, bias, res,
                                                   out, outb, act);
        } else {
            int node = nl2[it - I01];
            agg_group<D, MEAN_HEADS, RES_BF16, 64>(node, lane, wls, ssrc, offs,
                                                   deg, hb, el, er, bias, res,
                                                   out, outb, act);
        }
    }
}

// ---------------------------------------------------------------------------

extern "C" void kernel_launch(void* const* d_in, const int* in_sizes, int n_in,
                              void* d_out, int out_size, void* d_ws, size_t ws_size,
                              hipStream_t stream) {
    const float* x     = (const float*)d_in[0];
    const int*   esrc  = (const int*)d_in[1];
    const int*   edst  = (const int*)d_in[2];
    const float* W0    = (const float*)d_in[3];
    const float* al0   = (const float*)d_in[4];
    const float* ar0   = (const float*)d_in[5];
    const float* b0    = (const float*)d_in[6];
    const float* W1    = (const float*)d_in[7];
    const float* al1   = (const float*)d_in[8];
    const float* ar1   = (const float*)d_in[9];
    const float* b1    = (const float*)d_in[10];
    const float* W2    = (const float*)d_in[11];
    const float* al2   = (const float*)d_in[12];
    const float* ar2   = (const float*)d_in[13];
    const float* b2    = (const float*)d_in[14];
    const float* Wres2 = (const float*)d_in[15];

    const int N = in_sizes[0] / 256;  // 50000
    const int E = in_sizes[1];        // 800000

    // workspace layout
    float* ws = (float*)d_ws;
    float* hres  = ws;                      // [N,64]  L2 projected residual
    float* el    = hres + (size_t)N * 64;   // [N,2]
    float* er    = el + (size_t)N * 2;      // [N,2]
    int* deg     = (int*)(er + (size_t)N * 2);
    int* offs    = deg + N;
    int* bcur    = offs + N;                // [256] (196 used; meta at +208)
    int* bbase   = bcur + 256;              // [256] (unused; layout keep)
    int* ssrc    = bbase + 256;             // [E]
    uint* bdata  = (uint*)(ssrc + E);       // [NBK * BCAP]
    ushort* Hb   = (ushort*)(bdata + (size_t)NBK * BCAP);  // [N,128] bf16
    ushort* Ab   = Hb + (size_t)N * 128;    // [N,128] bf16 agg0 out
    ushort* Bb   = Ab + (size_t)N * 128;    // [N,128] bf16 agg1 out
    ushort* Wt0  = Bb + (size_t)N * 128;    // [128,256] bf16 W0^T
    ushort* Wt1  = Wt0 + 128 * 256;         // [128,128] bf16 W1^T
    ushort* Wt2c = Wt1 + 128 * 128;         // [128,128] bf16 [W2|Wres2]^T
    int* nl0     = (int*)(Wt2c + 128 * 128);  // [N] deg<=16
    int* nl1     = nl0 + N;                 // [N] 17..32
    int* nl2     = nl1 + N;                 // [N] >32
    int* meta    = bcur + 208;              // [3] class counts (memset w/ bcur)

    // ---- bucket-CSR build + weight prep (fused) ----
    hipMemsetAsync(bcur, 0, 256 * sizeof(int), stream);
    const int nba = (E + 2047) / 2048;  // 391
    buildA_k<<<nba + 256, 256, 0, stream>>>(esrc, edst, E, bcur, bdata, nba,
                                            W0, W1, W2, Wres2, Wt0, Wt1, Wt2c);

    const int gblk = (N + 127) / 128;  // 391
    const int ablk = 2048;             // 8192 waves, grid-stride over items

    // ---- Layer 0 GEMM fused with bucketB (independent work) ----
    gemm0_bucketB_k<<<gblk + NBK, 256, 0, stream>>>(
        x, Wt0, Hb, N, al0, ar0, el, er, gblk,
        bdata, bcur, deg, offs, ssrc, meta, nl0, nl1, nl2);
    agg_c2<64, false, false><<<ablk, 256, 0, stream>>>(
        meta, nl0, nl1, nl2, ssrc, offs, deg, Hb, el, er, b0, nullptr,
        nullptr, Ab, 1);

    // ---- Layer 1: 128 -> [N,2,64], identity residual (Ab, bf16), ELU ----
    gemm_m<128, false, false><<<gblk, 256, 0, stream>>>(
        nullptr, Ab, Wt1, Hb, nullptr, N, al1, ar1, el, er);
    agg_c2<64, false, true><<<ablk, 256, 0, stream>>>(
        meta, nl0, nl1, nl2, ssrc, offs, deg, Hb, el, er, b1, Ab,
        nullptr, Bb, 1);

    // ---- Layer 2: 128 -> [N,2,32], W2+Wres2 fused, head-mean ----
    gemm_m<128, true, false><<<gblk, 256, 0, stream>>>(
        nullptr, Bb, Wt2c, Hb, hres, N, al2, ar2, el, er);
    agg_c2<32, true, false><<<ablk, 256, 0, stream>>>(
        meta, nl0, nl1, nl2, ssrc, offs, deg, Hb, el, er, b2, hres,
        (float*)d_out, nullptr, 0);
}

// Round 5
// 263.432 us; speedup vs baseline: 1.1943x; 1.0407x over previous
//
#include <hip/hip_runtime.h>
#include <math.h>

// ---------------------------------------------------------------------------
// GAT, 3 layers, N=50000, E=800000, H=2 heads, D=64/64/32.
// Bucket-CSR build (2-pass, locality-aware); MFMA GEMM with B-panel-in-LDS
// (staged once, padded stride 136 -> 2-way banks only), A direct from global,
// zero barriers in the K-loop; fused el/er + bf16-h epilogue; bucketB hidden
// under gemm0; degree-binned aggregation (16/32/64 lanes/node), UB=8 gathers.
// ---------------------------------------------------------------------------

typedef unsigned int uint;
typedef unsigned short ushort;
typedef __attribute__((ext_vector_type(8))) short bf16x8;
typedef __attribute__((ext_vector_type(4))) float f32x4;

#define NBK 196     // buckets = ceil(50000/256); bucket = dst >> 8
#define BCAP 4608   // per-bucket capacity (mean 4082, sigma 64 -> +8 sigma)

__device__ inline uint f2bf(float f) {  // fp32 -> bf16 bits, RNE
    uint u = __float_as_uint(f);
    return (u + 0x7fffu + ((u >> 16) & 1u)) >> 16;
}

__device__ inline uint4 pack8(float4 a, float4 b) {
    return make_uint4(f2bf(a.x) | (f2bf(a.y) << 16), f2bf(a.z) | (f2bf(a.w) << 16),
                      f2bf(b.x) | (f2bf(b.y) << 16), f2bf(b.z) | (f2bf(b.w) << 16));
}

// ---------------------------------------------------------------------------
// Fused pass: blocks [0, nba) = bucketA (edges -> per-bucket append regions);
// blocks [nba, nba+256) = weight transpose+bf16 (independent inputs).
// ---------------------------------------------------------------------------
__global__ __launch_bounds__(256) void buildA_k(
    const int* __restrict__ src, const int* __restrict__ dst, int E,
    int* __restrict__ bcur, uint* __restrict__ bdata, int nba,
    const float* __restrict__ W0, const float* __restrict__ W1,
    const float* __restrict__ W2, const float* __restrict__ Wr,
    ushort* __restrict__ Wt0, ushort* __restrict__ Wt1,
    ushort* __restrict__ Wt2cat) {
    __shared__ int lhist[NBK];
    __shared__ int gbase[NBK];
    const int t = threadIdx.x;
    if ((int)blockIdx.x >= nba) {      // ---- weight-prep blocks ----
        int wb = blockIdx.x - nba;
        if (wb < 128) {                // W0: 32768 elems
            int i = wb * 256 + t;
            int n = i >> 8, k = i & 255;
            Wt0[n * 256 + k] = (ushort)f2bf(W0[k * 128 + n]);
        } else if (wb < 192) {         // W1: 16384
            int i = (wb - 128) * 256 + t;
            int n = i >> 7, k = i & 127;
            Wt1[n * 128 + k] = (ushort)f2bf(W1[k * 128 + n]);
        } else if (wb < 224) {         // W2: 8192
            int i = (wb - 192) * 256 + t;
            int n = i >> 7, k = i & 127;
            Wt2cat[n * 128 + k] = (ushort)f2bf(W2[k * 64 + n]);
        } else {                       // Wres2: 8192
            int i = (wb - 224) * 256 + t;
            int n = i >> 7, k = i & 127;
            Wt2cat[(64 + n) * 128 + k] = (ushort)f2bf(Wr[k * 64 + n]);
        }
        return;
    }
    // ---- bucketA blocks ----
    for (int i = t; i < NBK; i += 256) lhist[i] = 0;
    __syncthreads();
    const int e0 = blockIdx.x * 2048 + t * 8;
    uint payload[8], meta[8];
#pragma unroll
    for (int i = 0; i < 8; ++i) {
        int e = e0 + i;
        if (e < E) {
            int s = src[e], d = dst[e];
            int b = d >> 8;
            int r = atomicAdd(&lhist[b], 1);
            payload[i] = ((uint)s << 8) | (uint)(d & 255);
            meta[i] = ((uint)b << 16) | (uint)r;
        } else {
            meta[i] = 0xffffffffu;
        }
    }
    __syncthreads();
    for (int i = t; i < NBK; i += 256) {
        int c = lhist[i];
        gbase[i] = c ? atomicAdd(&bcur[i], c) : 0;
    }
    __syncthreads();
#pragma unroll
    for (int i = 0; i < 8; ++i) {
        if (meta[i] != 0xffffffffu) {
            int b = meta[i] >> 16;
            int pos = gbase[b] + (int)(meta[i] & 0xffffu);
            if (pos < BCAP) bdata[(size_t)b * BCAP + pos] = payload[i];
        }
    }
}

// ---------------------------------------------------------------------------
// Bucket pass B body (+ inline 196-bucket prefix scan + degree binning).
// LDS carved from caller's smem (overlaid with gemm smem in fused kernel).
// ---------------------------------------------------------------------------
__device__ void bucketB_body(
    float* smemf, int b, const uint* __restrict__ bdata,
    const int* __restrict__ bcur, int* __restrict__ deg,
    int* __restrict__ offs, int* __restrict__ ssrc, int n,
    int* __restrict__ meta, int* __restrict__ nl0, int* __restrict__ nl1,
    int* __restrict__ nl2) {
    int* lhist = (int*)smemf;        // 256
    int* lofs  = lhist + 256;        // 256
    int* lcur  = lofs + 256;         // 256
    int* stmp  = lcur + 256;         // 256
    int* lc    = stmp + 256;         // 3
    int* lb    = lc + 3;             // 3
    int* sgb   = lb + 3;             // 1
    const int t = threadIdx.x;
    const int cnt = min(bcur[b], BCAP);
    int cv = (t < NBK) ? min(bcur[t], BCAP) : 0;
    stmp[t] = cv;
    lhist[t] = 0;
    if (t < 3) lc[t] = 0;
    __syncthreads();
    for (int o = 1; o < 256; o <<= 1) {
        int add = (t >= o) ? stmp[t - o] : 0;
        __syncthreads();
        stmp[t] += add;
        __syncthreads();
    }
    if (t == 0) sgb[0] = b ? stmp[b - 1] : 0;
    __syncthreads();
    const int gb = sgb[0];
    const uint* bd = bdata + (size_t)b * BCAP;
    for (int i = t; i < cnt; i += 256)
        atomicAdd(&lhist[bd[i] & 255], 1);
    __syncthreads();
    int v = lhist[t];
    stmp[t] = v;
    __syncthreads();
    for (int o = 1; o < 256; o <<= 1) {
        int add = (t >= o) ? stmp[t - o] : 0;
        __syncthreads();
        stmp[t] += add;
        __syncthreads();
    }
    lofs[t] = stmp[t] - v;  // exclusive
    lcur[t] = 0;
    __syncthreads();
    int node = b * 256 + t;
    int cls = -1, r = 0;
    if (node < n) {
        deg[node] = v;
        offs[node] = gb + lofs[t];
        cls = (v <= 16) ? 0 : ((v <= 32) ? 1 : 2);
        r = atomicAdd(&lc[cls], 1);
    }
    __syncthreads();
    if (t < 3) lb[t] = lc[t] ? atomicAdd(&meta[t], lc[t]) : 0;
    __syncthreads();
    if (node < n) {
        int* nl = (cls == 0) ? nl0 : ((cls == 1) ? nl1 : nl2);
        nl[lb[cls] + r] = node;
    }
    for (int i = t; i < cnt; i += 256) {
        uint p = bd[i];
        int dl = p & 255;
        int rr = atomicAdd(&lcur[dl], 1);
        ssrc[gb + lofs[dl] + rr] = (int)(p >> 8);
    }
}

// ---------------------------------------------------------------------------
// MFMA GEMM body: C[64 rows x 128 cols] = A[rows,K] * Wt^T.
// B K-panel (128 x 136-padded bf16, 34.8KB) staged to LDS ONCE per 128-K
// chunk; A fragments loaded direct from global (streamed once); K-loop has
// ZERO barriers.  4 waves each own a 32-row x 64-col quadrant (acc[2][4]):
// each B-frag ds_read feeds 2 MFMA, each A-frag 4.  Epilogue Cs overlays Ws.
// Verified fragment layouts: A[m=lane&15][k=quad*8+j]; B from Bt[n][k] rows;
// C/D col=lane&15, row=quad*4+reg.
// ---------------------------------------------------------------------------
template <int K, bool L2MODE, bool AFP32>
__device__ void gemm_body(
    float* smem, const float* __restrict__ Af, const ushort* __restrict__ Ab,
    const ushort* __restrict__ Wt, ushort* __restrict__ Hb,
    float* __restrict__ hres, int nrows,
    const float* __restrict__ al, const float* __restrict__ ar,
    float* __restrict__ el, float* __restrict__ er, int bid) {
    constexpr int WS = 136;                   // padded LDS row stride (bf16)
    ushort* Ws = (ushort*)smem;               // 128 x 136 bf16 (34816 B)
    float* Cs = smem;                         // 64 x 132 fp32 (epilogue ovl)
    float* alr = smem + 8704;                 // staged al|ar (256 floats)
    const int tid = threadIdx.x;
    const int w = tid >> 6;
    const int lane = tid & 63;
    const int l15 = lane & 15, quad = lane >> 4;
    const int w2 = w >> 1;                    // row half (0/1)
    const int wc = w & 1;                     // col half (0/1)
    const int row0 = bid * 64;
    constexpr int NC = L2MODE ? 64 : 128;

    if (tid < 2 * NC) alr[tid] = (tid < NC) ? al[tid] : ar[tid - NC];

    const int ar0i = row0 + w2 * 32 + l15;    // A row for m=0
    const bool av0 = ar0i < nrows;
    const bool av1 = ar0i + 16 < nrows;

    f32x4 acc[2][4];
#pragma unroll
    for (int m = 0; m < 2; ++m)
#pragma unroll
        for (int i = 0; i < 4; ++i) acc[m][i] = (f32x4){0.f, 0.f, 0.f, 0.f};

    union BC { uint4 u; bf16x8 b; };

#pragma unroll
    for (int kh = 0; kh < K / 128; ++kh) {
        if (kh) __syncthreads();   // prior readers done before restage
        // ---- stage B K-panel: 128 rows x 128 cols -> Ws[128][136] ----
#pragma unroll
        for (int t = 0; t < 8; ++t) {
            int idx = tid + t * 256;
            int n = idx >> 4, c8 = idx & 15;
            *(uint4*)&Ws[n * WS + c8 * 8] =
                *(const uint4*)&Wt[(size_t)n * K + kh * 128 + c8 * 8];
        }
        __syncthreads();
        // ---- K-loop: no barriers ----
#pragma unroll
        for (int ks = 0; ks < 4; ++ks) {
            const int kc = kh * 128 + ks * 32 + quad * 8;
            bf16x8 af0 = {0, 0, 0, 0, 0, 0, 0, 0};
            bf16x8 af1 = {0, 0, 0, 0, 0, 0, 0, 0};
            if (AFP32) {
                if (av0) {
                    float4 v0 = *(const float4*)&Af[(size_t)ar0i * K + kc];
                    float4 v1 = *(const float4*)&Af[(size_t)ar0i * K + kc + 4];
                    BC cu; cu.u = pack8(v0, v1); af0 = cu.b;
                }
                if (av1) {
                    float4 v0 = *(const float4*)&Af[(size_t)(ar0i + 16) * K + kc];
                    float4 v1 = *(const float4*)&Af[(size_t)(ar0i + 16) * K + kc + 4];
                    BC cu; cu.u = pack8(v0, v1); af1 = cu.b;
                }
            } else {
                if (av0) af0 = *(const bf16x8*)&Ab[(size_t)ar0i * K + kc];
                if (av1) af1 = *(const bf16x8*)&Ab[(size_t)(ar0i + 16) * K + kc];
            }
#pragma unroll
            for (int ct = 0; ct < 4; ++ct) {
                bf16x8 bf = *(const bf16x8*)&Ws[(wc * 64 + ct * 16 + l15) * WS +
                                                ks * 32 + quad * 8];
                acc[0][ct] = __builtin_amdgcn_mfma_f32_16x16x32_bf16(af0, bf, acc[0][ct], 0, 0, 0);
                acc[1][ct] = __builtin_amdgcn_mfma_f32_16x16x32_bf16(af1, bf, acc[1][ct], 0, 0, 0);
            }
        }
    }
    __syncthreads();   // Ws dead; Cs overlay begins

    // ---- epilogue: C tile -> Cs (64 x 132 fp32); quadrants disjoint ----
#pragma unroll
    for (int m = 0; m < 2; ++m)
#pragma unroll
        for (int ct = 0; ct < 4; ++ct)
#pragma unroll
            for (int r = 0; r < 4; ++r)
                Cs[(w2 * 32 + m * 16 + quad * 4 + r) * 132 +
                   wc * 64 + ct * 16 + l15] = acc[m][ct][r];
    __syncthreads();

    if (L2MODE) {
#pragma unroll
        for (int t = 0; t < 2; ++t) {
            int chunk = tid + t * 256;
            int r = chunk >> 3, c8 = chunk & 7;
            int grow = row0 + r;
            if (grow < nrows) {
                float4 v0 = *(float4*)&Cs[r * 132 + c8 * 8];
                float4 v1 = *(float4*)&Cs[r * 132 + c8 * 8 + 4];
                *(uint4*)&Hb[(size_t)grow * 64 + c8 * 8] = pack8(v0, v1);
            }
        }
#pragma unroll
        for (int t = 0; t < 4; ++t) {
            int chunk = tid + t * 256;
            int r = chunk >> 4, c4 = chunk & 15;
            int grow = row0 + r;
            if (grow < nrows)
                *(float4*)&hres[(size_t)grow * 64 + c4 * 4] =
                    *(float4*)&Cs[r * 132 + 64 + c4 * 4];
        }
    } else {
#pragma unroll
        for (int t = 0; t < 4; ++t) {
            int chunk = tid + t * 256;
            int r = chunk >> 4, c8 = chunk & 15;
            int grow = row0 + r;
            if (grow < nrows) {
                float4 v0 = *(float4*)&Cs[r * 132 + c8 * 8];
                float4 v1 = *(float4*)&Cs[r * 132 + c8 * 8 + 4];
                *(uint4*)&Hb[(size_t)grow * 128 + c8 * 8] = pack8(v0, v1);
            }
        }
    }
    // el/er: 64 rows x 2 heads x {el,er} = 256 threads
    {
        constexpr int HD = L2MODE ? 32 : 64;
        int r = tid >> 2, hh = (tid >> 1) & 1, iser = tid & 1;
        int grow = row0 + r;
        const float* coef = alr + iser * NC + hh * HD;
        const float* crow = Cs + r * 132 + hh * HD;
        float sum = 0.f;
#pragma unroll
        for (int i = 0; i < HD; ++i) sum += crow[i] * coef[i];
        if (grow < nrows) (iser ? er : el)[grow * 2 + hh] = sum;
    }
}

// standalone GEMM kernel (layers 1, 2)
template <int K, bool L2MODE, bool AFP32>
__global__ __launch_bounds__(256) void gemm_m(
    const float* __restrict__ Af, const ushort* __restrict__ Ab,
    const ushort* __restrict__ Wt, ushort* __restrict__ Hb,
    float* __restrict__ hres, int nrows,
    const float* __restrict__ al, const float* __restrict__ ar,
    float* __restrict__ el, float* __restrict__ er) {
    __shared__ float smem[8960];
    gemm_body<K, L2MODE, AFP32>(smem, Af, Ab, Wt, Hb, hres, nrows, al, ar,
                                el, er, blockIdx.x);
}

// fused: blocks [0, gblk) = gemm0 (x * W0); blocks [gblk, gblk+NBK) = bucketB
__global__ __launch_bounds__(256) void gemm0_bucketB_k(
    const float* __restrict__ x, const ushort* __restrict__ Wt0,
    ushort* __restrict__ Hb, int nrows,
    const float* __restrict__ al, const float* __restrict__ ar,
    float* __restrict__ el, float* __restrict__ er, int gblk,
    const uint* __restrict__ bdata, const int* __restrict__ bcur,
    int* __restrict__ deg, int* __restrict__ offs, int* __restrict__ ssrc,
    int* __restrict__ meta, int* __restrict__ nl0, int* __restrict__ nl1,
    int* __restrict__ nl2) {
    __shared__ float smem[8960];
    if ((int)blockIdx.x < gblk) {
        gemm_body<256, false, true>(smem, x, nullptr, Wt0, Hb, nullptr, nrows,
                                    al, ar, el, er, blockIdx.x);
    } else {
        bucketB_body(smem, blockIdx.x - gblk, bdata, bcur, deg, offs, ssrc,
                     nrows, meta, nl0, nl1, nl2);
    }
}

// ---------------------------------------------------------------------------
// Aggregation for one node handled by LPN lanes (group-aligned within wave).
// LPN=16: 4 nodes/wave (deg<=16).  LPN=32: 2 nodes/wave (deg<=32).
// LPN=64: full wave; also handles deg>64 via online pass.
// UB=8: eight uint4 gathers in flight per lane (latency hiding).
// ---------------------------------------------------------------------------
template <int D, bool MEAN_HEADS, bool RES_BF16, int LPN>
__device__ __forceinline__ void agg_group(
    int node, int lane, float2* __restrict__ wlsw,
    const int* __restrict__ ssrc, const int* __restrict__ offs,
    const int* __restrict__ deg, const ushort* __restrict__ hb,
    const float* __restrict__ el, const float* __restrict__ er,
    const float* __restrict__ bias, const void* __restrict__ res,
    float* __restrict__ out, ushort* __restrict__ outb, int act) {
    constexpr int F = 2 * D;       // feats per row
    constexpr int CH = F / 8;      // uint4 chunks per row
    constexpr int ESL = LPN / CH;  // edge slots in flight per group
    constexpr int UB = 8;          // batched slots
    static_assert(ESL >= 1, "LPN must cover a full row");
    const int g = lane / LPN, sl = lane % LPN;
    const bool valid = node >= 0;
    float2* wls = wlsw + g * (LPN * 2);  // group staging: LPN edges x 2 heads
    int off = 0, dg = 0;
    float2 ern = make_float2(0.f, 0.f);
    if (valid) {
        off = offs[node];
        dg = deg[node];
        ern = *(const float2*)&er[node * 2];
    }
    const uint4* __restrict__ hp = (const uint4*)hb;
    const int c = sl & (CH - 1);
    const int es = sl / CH;
    const int h1 = (c >= CH / 2) ? 1 : 0;
    const float2* wbase = wls + es * 2 + h1;
    float acc[8];
#pragma unroll
    for (int i = 0; i < 8; ++i) acc[i] = 0.f;

    auto inner = [&](int cnt) {
        for (int p = 0; p < cnt; p += UB * ESL) {
            float2 mw[UB];
#pragma unroll
            for (int u = 0; u < UB; ++u) mw[u] = wbase[(p + u * ESL) * 2];
            uint4 q[UB];
#pragma unroll
            for (int u = 0; u < UB; ++u)
                q[u] = hp[(size_t)__float_as_int(mw[u].x) * CH + c];
#pragma unroll
            for (int u = 0; u < UB; ++u) {
                float wj = mw[u].y;
                acc[0] += wj * __uint_as_float(q[u].x << 16);
                acc[1] += wj * __uint_as_float(q[u].x & 0xffff0000u);
                acc[2] += wj * __uint_as_float(q[u].y << 16);
                acc[3] += wj * __uint_as_float(q[u].y & 0xffff0000u);
                acc[4] += wj * __uint_as_float(q[u].z << 16);
                acc[5] += wj * __uint_as_float(q[u].z & 0xffff0000u);
                acc[6] += wj * __uint_as_float(q[u].w << 16);
                acc[7] += wj * __uint_as_float(q[u].w & 0xffff0000u);
            }
        }
    };

    bool big = false;
    if constexpr (LPN == 64) big = (dg > 64);

    if (!big) {  // dg <= LPN: single staged pass, butterfly softmax over LPN
        int sidx = 0;
        float a = -INFINITY, b = -INFINITY;
        if (valid && sl < dg) {
            sidx = ssrc[off + sl];
            float2 ev = *(const float2*)&el[sidx * 2];
            a = ev.x + ern.x; a = fmaxf(a, 0.2f * a);
            b = ev.y + ern.y; b = fmaxf(b, 0.2f * b);
        }
        float m0 = a, m1 = b;
#pragma unroll
        for (int o = LPN / 2; o; o >>= 1) {
            m0 = fmaxf(m0, __shfl_xor(m0, o));
            m1 = fmaxf(m1, __shfl_xor(m1, o));
        }
        float p0 = (valid && sl < dg) ? __expf(a - m0) : 0.f;
        float p1 = (valid && sl < dg) ? __expf(b - m1) : 0.f;
        float s0 = p0, s1 = p1;
#pragma unroll
        for (int o = LPN / 2; o; o >>= 1) {
            s0 += __shfl_xor(s0, o);
            s1 += __shfl_xor(s1, o);
        }
        float is0 = s0 > 0.f ? 1.f / s0 : 0.f;
        float is1 = s1 > 0.f ? 1.f / s1 : 0.f;
        wls[sl * 2 + 0] = make_float2(__int_as_float(sidx), p0 * is0);
        wls[sl * 2 + 1] = make_float2(__int_as_float(sidx), p1 * is1);
        inner(dg);
    } else if constexpr (LPN == 64) {  // rare: deg > 64, online (m, s) pass
        float s0 = 0.f, s1 = 0.f;
        float m0 = -INFINITY, m1 = -INFINITY;
        for (int k = sl; k < dg; k += 64) {
            int sidx = ssrc[off + k];
            float2 ev = *(const float2*)&el[sidx * 2];
            float a = ev.x + ern.x; a = fmaxf(a, 0.2f * a);
            float b = ev.y + ern.y; b = fmaxf(b, 0.2f * b);
            float nm = fmaxf(m0, a);
            s0 = s0 * __expf(m0 - nm) + __expf(a - nm); m0 = nm;
            nm = fmaxf(m1, b);
            s1 = s1 * __expf(m1 - nm) + __expf(b - nm); m1 = nm;
        }
        for (int o = 32; o; o >>= 1) {
            float om = __shfl_xor(m0, o), os = __shfl_xor(s0, o);
            float nm = fmaxf(m0, om);
            s0 = (nm == -INFINITY) ? 0.f : s0 * __expf(m0 - nm) + os * __expf(om - nm);
            m0 = nm;
            om = __shfl_xor(m1, o); os = __shfl_xor(s1, o);
            nm = fmaxf(m1, om);
            s1 = (nm == -INFINITY) ? 0.f : s1 * __expf(m1 - nm) + os * __expf(om - nm);
            m1 = nm;
        }
        float is0 = s0 > 0.f ? 1.f / s0 : 0.f;
        float is1 = s1 > 0.f ? 1.f / s1 : 0.f;
        for (int cc = 0; cc < dg; cc += 64) {
            int k = cc + sl;
            int sidx = 0;
            float w0 = 0.f, w1 = 0.f;
            if (k < dg) {
                sidx = ssrc[off + k];
                float2 ev = *(const float2*)&el[sidx * 2];
                float a = ev.x + ern.x; a = fmaxf(a, 0.2f * a);
                float b = ev.y + ern.y; b = fmaxf(b, 0.2f * b);
                w0 = __expf(a - m0) * is0;
                w1 = __expf(b - m1) * is1;
            }
            wls[sl * 2 + 0] = make_float2(__int_as_float(sidx), w0);
            wls[sl * 2 + 1] = make_float2(__int_as_float(sidx), w1);
            inner(min(64, dg - cc));
        }
    }

    // cross-slot reduce (within group); no-op when LPN == CH
#pragma unroll
    for (int o = CH; o < LPN; o <<= 1) {
#pragma unroll
        for (int i = 0; i < 8; ++i) acc[i] += __shfl_xor(acc[i], o);
    }
    if (!valid) return;

    const int f0 = c * 8;
    float4 b0v = *(const float4*)&bias[f0];
    float4 b1v = *(const float4*)&bias[f0 + 4];
    float vv[8] = {acc[0] + b0v.x, acc[1] + b0v.y, acc[2] + b0v.z, acc[3] + b0v.w,
                   acc[4] + b1v.x, acc[5] + b1v.y, acc[6] + b1v.z, acc[7] + b1v.w};
    if (res) {
        if (RES_BF16) {
            uint4 r = ((const uint4*)res)[(size_t)node * CH + c];
            vv[0] += __uint_as_float(r.x << 16);
            vv[1] += __uint_as_float(r.x & 0xffff0000u);
            vv[2] += __uint_as_float(r.y << 16);
            vv[3] += __uint_as_float(r.y & 0xffff0000u);
            vv[4] += __uint_as_float(r.z << 16);
            vv[5] += __uint_as_float(r.z & 0xffff0000u);
            vv[6] += __uint_as_float(r.w << 16);
            vv[7] += __uint_as_float(r.w & 0xffff0000u);
        } else {
            const float* rf = (const float*)res;
            float4 r0v = *(const float4*)&rf[(size_t)node * F + f0];
            float4 r1v = *(const float4*)&rf[(size_t)node * F + f0 + 4];
            vv[0] += r0v.x; vv[1] += r0v.y; vv[2] += r0v.z; vv[3] += r0v.w;
            vv[4] += r1v.x; vv[5] += r1v.y; vv[6] += r1v.z; vv[7] += r1v.w;
        }
    }
    if (act) {
#pragma unroll
        for (int i = 0; i < 8; ++i)
            vv[i] = vv[i] > 0.f ? vv[i] : __expf(vv[i]) - 1.f;
    }
    if (MEAN_HEADS) {
        float ov[8];
#pragma unroll
        for (int i = 0; i < 8; ++i) ov[i] = __shfl_xor(vv[i], CH / 2);
        if (es == 0 && c < CH / 2) {
            float4 u0 = make_float4(0.5f * (vv[0] + ov[0]), 0.5f * (vv[1] + ov[1]),
                                    0.5f * (vv[2] + ov[2]), 0.5f * (vv[3] + ov[3]));
            float4 u1 = make_float4(0.5f * (vv[4] + ov[4]), 0.5f * (vv[5] + ov[5]),
                                    0.5f * (vv[6] + ov[6]), 0.5f * (vv[7] + ov[7]));
            *(float4*)&out[(size_t)node * D + f0] = u0;
            *(float4*)&out[(size_t)node * D + f0 + 4] = u1;
        }
    } else if (es == 0) {
        if (out) {
            *(float4*)&out[(size_t)node * F + f0] =
                make_float4(vv[0], vv[1], vv[2], vv[3]);
            *(float4*)&out[(size_t)node * F + f0 + 4] =
                make_float4(vv[4], vv[5], vv[6], vv[7]);
        }
        if (outb) {
            *(uint4*)&outb[(size_t)node * F + f0] =
                pack8(make_float4(vv[0], vv[1], vv[2], vv[3]),
                      make_float4(vv[4], vv[5], vv[6], vv[7]));
        }
    }
}

// ---------------------------------------------------------------------------
// Degree-binned aggregation driver: grid-strides over flattened item space
// [class0 items (4 nodes) | class1 items (2 nodes) | class2 items (1 node)].
// Item-space bounds computed from raw class counts (meta[0..2]).
// ---------------------------------------------------------------------------
template <int D, bool MEAN_HEADS, bool RES_BF16>
__global__ __launch_bounds__(256) void agg_c2(
    const int* __restrict__ meta, const int* __restrict__ nl0,
    const int* __restrict__ nl1, const int* __restrict__ nl2,
    const int* __restrict__ ssrc, const int* __restrict__ offs,
    const int* __restrict__ deg, const ushort* __restrict__ hb,
    const float* __restrict__ el, const float* __restrict__ er,
    const float* __restrict__ bias, const void* __restrict__ res,
    float* __restrict__ out, ushort* __restrict__ outb, int act) {
    __shared__ float2 wls_all[4][128];   // per-wave staging
    const int wid = threadIdx.x >> 6;
    const int lane = threadIdx.x & 63;
    float2* wls = wls_all[wid];
    const int c0 = meta[0], c1 = meta[1], c2 = meta[2];
    const int I0 = (c0 + 3) >> 2;
    const int I01 = I0 + ((c1 + 1) >> 1);
    const int T = I01 + c2;
    const int nW = gridDim.x * 4;
    for (int it = blockIdx.x * 4 + wid; it < T; it += nW) {
        if (it < I0) {
            int idx = it * 4 + (lane >> 4);
            int node = (idx < c0) ? nl0[idx] : -1;
            agg_group<D, MEAN_HEADS, RES_BF16, 16>(node, lane, wls, ssrc, offs,
                                                   deg, hb, el, er, bias, res,
                                                   out, outb, act);
        } else if (it < I01) {
            int idx = (it - I0) * 2 + (lane >> 5);
            int node = (idx < c1) ? nl1[idx] : -1;
            agg_group<D, MEAN_HEADS, RES_BF16, 32>(node, lane, wls, ssrc, offs,
                                                   deg, hb, el, er, bias, res,
                                                   out, outb, act);
        } else {
            int node = nl2[it - I01];
            agg_group<D, MEAN_HEADS, RES_BF16, 64>(node, lane, wls, ssrc, offs,
                                                   deg, hb, el, er, bias, res,
                                                   out, outb, act);
        }
    }
}

// ---------------------------------------------------------------------------

extern "C" void kernel_launch(void* const* d_in, const int* in_sizes, int n_in,
                              void* d_out, int out_size, void* d_ws, size_t ws_size,
                              hipStream_t stream) {
    const float* x     = (const float*)d_in[0];
    const int*   esrc  = (const int*)d_in[1];
    const int*   edst  = (const int*)d_in[2];
    const float* W0    = (const float*)d_in[3];
    const float* al0   = (const float*)d_in[4];
    const float* ar0   = (const float*)d_in[5];
    const float* b0    = (const float*)d_in[6];
    const float* W1    = (const float*)d_in[7];
    const float* al1   = (const float*)d_in[8];
    const float* ar1   = (const float*)d_in[9];
    const float* b1    = (const float*)d_in[10];
    const float* W2    = (const float*)d_in[11];
    const float* al2   = (const float*)d_in[12];
    const float* ar2   = (const float*)d_in[13];
    const float* b2    = (const float*)d_in[14];
    const float* Wres2 = (const float*)d_in[15];

    const int N = in_sizes[0] / 256;  // 50000
    const int E = in_sizes[1];        // 800000

    // workspace layout
    float* ws = (float*)d_ws;
    float* hres  = ws;                      // [N,64]  L2 projected residual
    float* el    = hres + (size_t)N * 64;   // [N,2]
    float* er    = el + (size_t)N * 2;      // [N,2]
    int* deg     = (int*)(er + (size_t)N * 2);
    int* offs    = deg + N;
    int* bcur    = offs + N;                // [256] (196 used; meta at +208)
    int* bbase   = bcur + 256;              // [256] (unused; layout keep)
    int* ssrc    = bbase + 256;             // [E]
    uint* bdata  = (uint*)(ssrc + E);       // [NBK * BCAP]
    ushort* Hb   = (ushort*)(bdata + (size_t)NBK * BCAP);  // [N,128] bf16
    ushort* Ab   = Hb + (size_t)N * 128;    // [N,128] bf16 agg0 out
    ushort* Bb   = Ab + (size_t)N * 128;    // [N,128] bf16 agg1 out
    ushort* Wt0  = Bb + (size_t)N * 128;    // [128,256] bf16 W0^T
    ushort* Wt1  = Wt0 + 128 * 256;         // [128,128] bf16 W1^T
    ushort* Wt2c = Wt1 + 128 * 128;         // [128,128] bf16 [W2|Wres2]^T
    int* nl0     = (int*)(Wt2c + 128 * 128);  // [N] deg<=16
    int* nl1     = nl0 + N;                 // [N] 17..32
    int* nl2     = nl1 + N;                 // [N] >32
    int* meta    = bcur + 208;              // [3] class counts (memset w/ bcur)

    // ---- bucket-CSR build + weight prep (fused) ----
    hipMemsetAsync(bcur, 0, 256 * sizeof(int), stream);
    const int nba = (E + 2047) / 2048;  // 391
    buildA_k<<<nba + 256, 256, 0, stream>>>(esrc, edst, E, bcur, bdata, nba,
                                            W0, W1, W2, Wres2, Wt0, Wt1, Wt2c);

    const int gblk = (N + 63) / 64;   // 782
    const int ablk = 2048;            // 8192 waves, grid-stride over items

    // ---- Layer 0 GEMM fused with bucketB (independent work) ----
    gemm0_bucketB_k<<<gblk + NBK, 256, 0, stream>>>(
        x, Wt0, Hb, N, al0, ar0, el, er, gblk,
        bdata, bcur, deg, offs, ssrc, meta, nl0, nl1, nl2);
    agg_c2<64, false, false><<<ablk, 256, 0, stream>>>(
        meta, nl0, nl1, nl2, ssrc, offs, deg, Hb, el, er, b0, nullptr,
        nullptr, Ab, 1);

    // ---- Layer 1: 128 -> [N,2,64], identity residual (Ab, bf16), ELU ----
    gemm_m<128, false, false><<<gblk, 256, 0, stream>>>(
        nullptr, Ab, Wt1, Hb, nullptr, N, al1, ar1, el, er);
    agg_c2<64, false, true><<<ablk, 256, 0, stream>>>(
        meta, nl0, nl1, nl2, ssrc, offs, deg, Hb, el, er, b1, Ab,
        nullptr, Bb, 1);

    // ---- Layer 2: 128 -> [N,2,32], W2+Wres2 fused, head-mean ----
    gemm_m<128, true, false><<<gblk, 256, 0, stream>>>(
        nullptr, Bb, Wt2c, Hb, hres, N, al2, ar2, el, er);
    agg_c2<32, true, false><<<ablk, 256, 0, stream>>>(
        meta, nl0, nl1, nl2, ssrc, offs, deg, Hb, el, er, b2, hres,
        (float*)d_out, nullptr, 0);
}